// Round 1
// baseline (220.841 us; speedup 1.0000x reference)
//
#include <hip/hip_runtime.h>
#include <math.h>

#define NB 128           // batches
#define IH 512
#define IW 512
#define NPIX (IH * IW)   // 262144
#define PARTS 8          // blocks per batch for the big passes
#define ROWS_PER_PART (IH / PARTS)          // 64
#define NTHREADS 256
#define GROUPS_PER_ROW (IW / 4)             // 128 float4 groups
#define TASKS (ROWS_PER_PART * GROUPS_PER_ROW) // 8192 per block
#define EPS_NORM 1e-6f
#define EPS_LOG 1e-8f

// ws layout (floats):
// [0, NB*PARTS)              partial min per (batch,part)
// [NB*PARTS, 2*NB*PARTS)     partial max
// [2*NB*PARTS, +NB)          S1 = sum(dn)
// [.. +NB)                   S2 = sum(dn^2)
// [.. +NB)                   S3 = sum(dn*log(dn+eps))
#define WS_PMIN 0
#define WS_PMAX (NB * PARTS)
#define WS_SUMS (2 * NB * PARTS)

// d for 4 consecutive cols [j, j+4) of row i (j % 4 == 0, 16B aligned)
__device__ __forceinline__ float4 compute_d(const float* __restrict__ img, int i, int j) {
    const float4 a = *reinterpret_cast<const float4*>(img + i * IW + j);
    float s0 = 0.f, s1 = 0.f, s2 = 0.f, s3 = 0.f;
    if (i < IH - 1) {
        const float4 r = *reinterpret_cast<const float4*>(img + (i + 1) * IW + j);
        s0 = r.y; s1 = r.z; s2 = r.w;
        // element j+3 needs img[i+1][j+4]; when j+3 == IW-1 the shifted value is 0
        s3 = (j + 4 < IW) ? img[(i + 1) * IW + j + 4] : 0.f;
    }
    return make_float4(fabsf(a.x - s0), fabsf(a.y - s1), fabsf(a.z - s2), fabsf(a.w - s3));
}

__global__ __launch_bounds__(NTHREADS) void k_minmax(const float* __restrict__ x,
                                                     float* __restrict__ ws) {
    const int b    = blockIdx.x / PARTS;
    const int part = blockIdx.x % PARTS;
    const float* img = x + (size_t)b * NPIX;
    const int t = threadIdx.x;

    float vmin = 3.4028235e38f, vmax = 0.f;  // d >= 0
    for (int task = t; task < TASKS; task += NTHREADS) {
        const int i = part * ROWS_PER_PART + (task >> 7);
        const int j = (task & 127) << 2;
        const float4 d = compute_d(img, i, j);
        vmin = fminf(vmin, fminf(fminf(d.x, d.y), fminf(d.z, d.w)));
        vmax = fmaxf(vmax, fmaxf(fmaxf(d.x, d.y), fmaxf(d.z, d.w)));
    }
    // wave64 butterfly then cross-wave via LDS
    #pragma unroll
    for (int off = 32; off > 0; off >>= 1) {
        vmin = fminf(vmin, __shfl_down(vmin, off, 64));
        vmax = fmaxf(vmax, __shfl_down(vmax, off, 64));
    }
    __shared__ float smin[NTHREADS / 64], smax[NTHREADS / 64];
    const int wave = t >> 6, lane = t & 63;
    if (lane == 0) { smin[wave] = vmin; smax[wave] = vmax; }
    __syncthreads();
    if (t == 0) {
        float m = smin[0], M = smax[0];
        #pragma unroll
        for (int w = 1; w < NTHREADS / 64; ++w) { m = fminf(m, smin[w]); M = fmaxf(M, smax[w]); }
        ws[WS_PMIN + blockIdx.x] = m;
        ws[WS_PMAX + blockIdx.x] = M;
        if (part == 0) {  // zero the sum slots for this batch (ws is poisoned)
            float* sums = ws + WS_SUMS;
            sums[b] = 0.f; sums[NB + b] = 0.f; sums[2 * NB + b] = 0.f;
        }
    }
}

__global__ __launch_bounds__(NTHREADS) void k_sums(const float* __restrict__ x,
                                                   float* __restrict__ ws) {
    const int b    = blockIdx.x / PARTS;
    const int part = blockIdx.x % PARTS;
    const float* img = x + (size_t)b * NPIX;
    const int t = threadIdx.x;

    // fold the 8 partials (uniform addresses -> broadcast loads)
    float dmin = ws[WS_PMIN + b * PARTS], dmax = ws[WS_PMAX + b * PARTS];
    #pragma unroll
    for (int p = 1; p < PARTS; ++p) {
        dmin = fminf(dmin, ws[WS_PMIN + b * PARTS + p]);
        dmax = fmaxf(dmax, ws[WS_PMAX + b * PARTS + p]);
    }
    const float invR = 1.0f / (dmax - dmin + EPS_NORM);

    float s1 = 0.f, s2 = 0.f, s3 = 0.f;
    for (int task = t; task < TASKS; task += NTHREADS) {
        const int i = part * ROWS_PER_PART + (task >> 7);
        const int j = (task & 127) << 2;
        const float4 d = compute_d(img, i, j);
        {
            const float dn = (d.x - dmin) * invR;
            s1 += dn; s2 += dn * dn; s3 += dn * logf(dn + EPS_LOG);
        }
        {
            const float dn = (d.y - dmin) * invR;
            s1 += dn; s2 += dn * dn; s3 += dn * logf(dn + EPS_LOG);
        }
        {
            const float dn = (d.z - dmin) * invR;
            s1 += dn; s2 += dn * dn; s3 += dn * logf(dn + EPS_LOG);
        }
        {
            const float dn = (d.w - dmin) * invR;
            s1 += dn; s2 += dn * dn; s3 += dn * logf(dn + EPS_LOG);
        }
    }
    #pragma unroll
    for (int off = 32; off > 0; off >>= 1) {
        s1 += __shfl_down(s1, off, 64);
        s2 += __shfl_down(s2, off, 64);
        s3 += __shfl_down(s3, off, 64);
    }
    __shared__ float sh1[NTHREADS / 64], sh2[NTHREADS / 64], sh3[NTHREADS / 64];
    const int wave = t >> 6, lane = t & 63;
    if (lane == 0) { sh1[wave] = s1; sh2[wave] = s2; sh3[wave] = s3; }
    __syncthreads();
    if (t == 0) {
        float a1 = sh1[0], a2 = sh2[0], a3 = sh3[0];
        #pragma unroll
        for (int w = 1; w < NTHREADS / 64; ++w) { a1 += sh1[w]; a2 += sh2[w]; a3 += sh3[w]; }
        float* sums = ws + WS_SUMS;
        atomicAdd(&sums[b], a1);
        atomicAdd(&sums[NB + b], a2);
        atomicAdd(&sums[2 * NB + b], a3);
    }
}

__global__ void k_final(const float* __restrict__ ws, float* __restrict__ out) {
    const int b = threadIdx.x;
    if (b >= NB) return;
    const float* sums = ws + WS_SUMS;
    const float S1 = sums[b], S2 = sums[NB + b], S3 = sums[2 * NB + b];
    const float N = (float)NPIX;
    const float mean = S1 / N;
    float contrast = S2 - S1 * S1 / N;
    if (contrast < 0.f) contrast = 0.f;
    const float var = contrast / (N - 1.0f);
    const float stdv = sqrtf(var);
    const float entropy = -S3;
    const float smooth = 1.0f - 1.0f / (1.0f + var);
    float* o = out + b * 6;
    o[0] = mean; o[1] = stdv; o[2] = S2; o[3] = entropy; o[4] = contrast; o[5] = smooth;
}

extern "C" void kernel_launch(void* const* d_in, const int* in_sizes, int n_in,
                              void* d_out, int out_size, void* d_ws, size_t ws_size,
                              hipStream_t stream) {
    const float* x = (const float*)d_in[0];
    float* out = (float*)d_out;
    float* ws = (float*)d_ws;

    k_minmax<<<NB * PARTS, NTHREADS, 0, stream>>>(x, ws);
    k_sums  <<<NB * PARTS, NTHREADS, 0, stream>>>(x, ws);
    k_final <<<1, NB, 0, stream>>>(ws, out);
}